// Round 15
// baseline (1495.850 us; speedup 1.0000x reference)
//
#include <hip/hip_runtime.h>
#include <hip/hip_fp16.h>

// ---------------------------------------------------------------------------
// 2-layer GCN, bucket-local aggregation (NO CSR, no rp/adj):
//   k_hist -> scans -> k_bin : edges bucket-sorted into bbuf
//             (packed (d&1023)<<18 | s; bucket = 1024 dst nodes)
//   k_degb  : per-bucket LDS degree histogram -> dinv
//   k_mm1   : h1s = dinv*(x@W1), fp16 lo/hi 8-ch tables (3.2 MB, L2-fit)
//   k_aggb  : one block per bucket, LDS f32 acc[1024][8] (stride 9 to
//             spread banks); per edge: 1 random 16 B hs-row load + 8 LDS
//             atomics; epilogue adds self row, applies dinv (+bias,relu),
//             writes z1s (fp16) or pre (f32).  4 passes (L1/L2 x lo/hi).
//   k_out   : out = [preL|preH] @ W2 + b2
// Replaces round-14's k_bucket + 4x CSR gathers (~230 us aggregate): the
// gathers re-walked adj per (node,chpair); here each edge is touched once
// per pass with the same single random table read.
// bbuf stays live through both layers; tables live in the freed rp/adj
// space. Packing needs n < 2^18 (200000 ok).
// ---------------------------------------------------------------------------

#define TPB 256
#define BINT 256
#define SEGROWS 64
#define BUCKSH 10                 // log2(nodes per bucket)
#define BUCKN (1 << BUCKSH)       // 1024 nodes per bucket
#define MMN 32                    // nodes per mm1 tile

__device__ __forceinline__ int clampi(int v, int n) {
    return v < 0 ? 0 : (v >= n ? n - 1 : v);
}

// --- per-block LDS histogram over contiguous edge range ------------------
__global__ __launch_bounds__(BINT) void k_hist(const int* __restrict__ dst,
                                               int E, int n, int nbuck,
                                               int chunk,
                                               int* __restrict__ hist) {
    __shared__ int lh[256];
    const int b = blockIdx.x;
    const int t = threadIdx.x;
    lh[t] = 0;
    __syncthreads();
    const int start = b * chunk;
    const int end = min(E, start + chunk);
    int i = start + t;
    for (; i + 3 * BINT < end; i += 4 * BINT) {
        int d0 = clampi(dst[i], n);
        int d1 = clampi(dst[i + BINT], n);
        int d2 = clampi(dst[i + 2 * BINT], n);
        int d3 = clampi(dst[i + 3 * BINT], n);
        atomicAdd(&lh[d0 >> BUCKSH], 1);
        atomicAdd(&lh[d1 >> BUCKSH], 1);
        atomicAdd(&lh[d2 >> BUCKSH], 1);
        atomicAdd(&lh[d3 >> BUCKSH], 1);
    }
    for (; i < end; i += BINT) atomicAdd(&lh[clampi(dst[i], n) >> BUCKSH], 1);
    __syncthreads();
    for (int k = t; k < nbuck; k += BINT) hist[b * nbuck + k] = lh[k];
}

// --- segmented column scan stage 1: per-segment column sums --------------
__global__ void k_scanA1(const int* __restrict__ hist, int nbuck,
                         int* __restrict__ segsum) {
    int k = blockIdx.x * blockDim.x + threadIdx.x;
    int seg = blockIdx.y;
    if (k >= nbuck) return;
    const int* row = hist + (size_t)seg * SEGROWS * nbuck + k;
    int sum = 0;
#pragma unroll
    for (int b = 0; b < SEGROWS; ++b) sum += row[(size_t)b * nbuck];
    segsum[seg * nbuck + k] = sum;
}

// --- stage 2: serial scan over segments (nseg <= 32) + colsum ------------
__global__ void k_scanA2(int* __restrict__ segsum, int nbuck, int nseg,
                         int* __restrict__ colsum) {
    int k = blockIdx.x * blockDim.x + threadIdx.x;
    if (k >= nbuck) return;
    int run = 0;
    for (int sg = 0; sg < nseg; ++sg) {
        int v = segsum[sg * nbuck + k];
        segsum[sg * nbuck + k] = run;
        run += v;
    }
    colsum[k] = run;
}

// --- exclusive scan of colsum -> bstart[0..nbuck] ------------------------
__global__ void k_scanB(const int* __restrict__ colsum, int nbuck, int E,
                        int* __restrict__ bstart) {
    __shared__ int s[256];
    const int t = threadIdx.x;
    int loc[4];
    int a = 0;
#pragma unroll
    for (int i = 0; i < 4; ++i) {
        int idx = 4 * t + i;
        loc[i] = (idx < nbuck) ? colsum[idx] : 0;
        a += loc[i];
    }
    s[t] = a;
    __syncthreads();
#pragma unroll
    for (int off = 1; off < 256; off <<= 1) {
        int v = (t >= off) ? s[t - off] : 0;
        __syncthreads();
        s[t] += v;
        __syncthreads();
    }
    int base = s[t] - a;
#pragma unroll
    for (int i = 0; i < 4; ++i) {
        int idx = 4 * t + i;
        if (idx < nbuck) bstart[idx] = base;
        base += loc[i];
    }
    if (t == 255) bstart[nbuck] = E;
}

// --- stage 3: rewrite hist rows to global exclusive prefix ---------------
__global__ void k_scanA3(int* __restrict__ hist, int nbuck,
                         const int* __restrict__ segsum) {
    int k = blockIdx.x * blockDim.x + threadIdx.x;
    int seg = blockIdx.y;
    if (k >= nbuck) return;
    int run = segsum[seg * nbuck + k];
    int* row = hist + (size_t)seg * SEGROWS * nbuck + k;
#pragma unroll
    for (int b = 0; b < SEGROWS; ++b) {
        int v = row[(size_t)b * nbuck];
        row[(size_t)b * nbuck] = run;
        run += v;
    }
}

// --- binning: LDS cursors, LDS atomics only; 4-way ILP -------------------
__global__ __launch_bounds__(BINT) void k_bin(const int* __restrict__ src,
                                              const int* __restrict__ dst,
                                              int E, int n, int nbuck,
                                              int chunk,
                                              const int* __restrict__ hist,
                                              const int* __restrict__ bstart,
                                              int* __restrict__ bbuf) {
    __shared__ int lcur[256];
    const int b = blockIdx.x;
    const int t = threadIdx.x;
    for (int k = t; k < nbuck; k += BINT)
        lcur[k] = bstart[k] + hist[b * nbuck + k];
    __syncthreads();
    const int start = b * chunk;
    const int end = min(E, start + chunk);
    int i = start + t;
    for (; i + 3 * BINT < end; i += 4 * BINT) {
        int s0 = clampi(src[i], n);
        int s1 = clampi(src[i + BINT], n);
        int s2 = clampi(src[i + 2 * BINT], n);
        int s3 = clampi(src[i + 3 * BINT], n);
        int d0 = clampi(dst[i], n);
        int d1 = clampi(dst[i + BINT], n);
        int d2 = clampi(dst[i + 2 * BINT], n);
        int d3 = clampi(dst[i + 3 * BINT], n);
        int p0 = atomicAdd(&lcur[d0 >> BUCKSH], 1);
        int p1 = atomicAdd(&lcur[d1 >> BUCKSH], 1);
        int p2 = atomicAdd(&lcur[d2 >> BUCKSH], 1);
        int p3 = atomicAdd(&lcur[d3 >> BUCKSH], 1);
        bbuf[p0] = ((d0 & (BUCKN - 1)) << 18) | s0;
        bbuf[p1] = ((d1 & (BUCKN - 1)) << 18) | s1;
        bbuf[p2] = ((d2 & (BUCKN - 1)) << 18) | s2;
        bbuf[p3] = ((d3 & (BUCKN - 1)) << 18) | s3;
    }
    for (; i < end; i += BINT) {
        int s0 = clampi(src[i], n);
        int d0 = clampi(dst[i], n);
        int p0 = atomicAdd(&lcur[d0 >> BUCKSH], 1);
        bbuf[p0] = ((d0 & (BUCKN - 1)) << 18) | s0;
    }
}

// --- per-bucket degree -> dinv -------------------------------------------
__global__ __launch_bounds__(1024) void k_degb(const int* __restrict__ bbuf,
                                               const int* __restrict__ bstart,
                                               int n,
                                               float* __restrict__ dinv) {
    __shared__ int lcnt[1024];
    const int b = blockIdx.x;
    const int t = threadIdx.x;
    const int start = bstart[b];
    const int end = bstart[b + 1];
    lcnt[t] = 0;
    __syncthreads();
    int i = start + t;
    for (; i + 3 * 1024 < end; i += 4 * 1024) {
        int p0 = bbuf[i], p1 = bbuf[i + 1024], p2 = bbuf[i + 2048],
            p3 = bbuf[i + 3072];
        atomicAdd(&lcnt[((unsigned)p0) >> 18], 1);
        atomicAdd(&lcnt[((unsigned)p1) >> 18], 1);
        atomicAdd(&lcnt[((unsigned)p2) >> 18], 1);
        atomicAdd(&lcnt[((unsigned)p3) >> 18], 1);
    }
    for (; i < end; i += 1024) atomicAdd(&lcnt[((unsigned)bbuf[i]) >> 18], 1);
    __syncthreads();
    const int v = (b << BUCKSH) + t;
    if (v < n) dinv[v] = rsqrtf((float)(lcnt[t] + 1));
}

// --- h1s = dinv*(x@W1): LDS-staged tile (32 nodes), 512 thr --------------
__global__ __launch_bounds__(512) void k_mm1(const float* __restrict__ x,
                                             const float* __restrict__ W,
                                             const float* __restrict__ dinv,
                                             int n, __half* __restrict__ hlo,
                                             __half* __restrict__ hhi) {
    __shared__ float Ws[128 * 16];
    __shared__ float xs[MMN * 132];
    const int t = threadIdx.x;
    for (int i = t; i < 128 * 16; i += 512) Ws[i] = W[i];
    const int node0 = blockIdx.x * MMN;
    {
        const float4* xg = (const float4*)(x + (size_t)node0 * 128);
#pragma unroll
        for (int it = 0; it < 2; ++it) {
            int idx = it * 512 + t;
            int row = idx >> 5;
            int c4 = idx & 31;
            if (node0 + row < n) {
                float4 v = xg[(size_t)row * 32 + c4];
                float* dp = &xs[row * 132 + c4 * 4];
                dp[0] = v.x;
                dp[1] = v.y;
                dp[2] = v.z;
                dp[3] = v.w;
            }
        }
    }
    __syncthreads();
    const int node = node0 + (t >> 4);
    const int c = t & 15;
    if (node < n) {
        const float4* xr4 = (const float4*)&xs[(t >> 4) * 132];
        float acc = 0.f;
#pragma unroll
        for (int q = 0; q < 32; ++q) {
            float4 xv = xr4[q];
            acc += xv.x * Ws[(4 * q + 0) * 16 + c] +
                   xv.y * Ws[(4 * q + 1) * 16 + c] +
                   xv.z * Ws[(4 * q + 2) * 16 + c] +
                   xv.w * Ws[(4 * q + 3) * 16 + c];
        }
        __half hv = __float2half(dinv[node] * acc);
        if (c < 8)
            hlo[(size_t)node * 8 + c] = hv;
        else
            hhi[(size_t)node * 8 + (c - 8)] = hv;
    }
}

// --- bucket-local aggregation over an 8-ch fp16 table --------------------
// acc stride 9 (coprime with 32 banks). Per edge: one 16 B row load + 8 LDS
// float atomics. Epilogue adds self row, scales by dinv (+bias/relu for L1).
__device__ __forceinline__ void unpack8(float4 r, float* f) {
    const __half2* hp = (const __half2*)&r;
#pragma unroll
    for (int q = 0; q < 4; ++q) {
        f[2 * q] = __low2float(hp[q]);
        f[2 * q + 1] = __high2float(hp[q]);
    }
}

template <bool L1>
__global__ __launch_bounds__(1024) void k_aggb(
    const int* __restrict__ bbuf, const int* __restrict__ bstart,
    const float* __restrict__ dinv, const __half* __restrict__ hs,
    const float* __restrict__ bias, int ch0, void* __restrict__ o, int n) {
    __shared__ float acc[BUCKN * 9];
    const int b = blockIdx.x;
    const int t = threadIdx.x;
    for (int i = t; i < BUCKN * 9; i += 1024) acc[i] = 0.f;
    __syncthreads();
    const int start = bstart[b];
    const int end = bstart[b + 1];
    int i = start + t;
    for (; i + 3 * 1024 < end; i += 4 * 1024) {
        int p0 = bbuf[i], p1 = bbuf[i + 1024], p2 = bbuf[i + 2048],
            p3 = bbuf[i + 3072];
        float4 r0 = *(const float4*)(hs + (size_t)(p0 & 0x3FFFF) * 8);
        float4 r1 = *(const float4*)(hs + (size_t)(p1 & 0x3FFFF) * 8);
        float4 r2 = *(const float4*)(hs + (size_t)(p2 & 0x3FFFF) * 8);
        float4 r3 = *(const float4*)(hs + (size_t)(p3 & 0x3FFFF) * 8);
        float f0[8], f1[8], f2[8], f3[8];
        unpack8(r0, f0);
        unpack8(r1, f1);
        unpack8(r2, f2);
        unpack8(r3, f3);
        int b0 = (((unsigned)p0) >> 18) * 9;
        int b1 = (((unsigned)p1) >> 18) * 9;
        int b2 = (((unsigned)p2) >> 18) * 9;
        int b3 = (((unsigned)p3) >> 18) * 9;
#pragma unroll
        for (int q = 0; q < 8; ++q) atomicAdd(&acc[b0 + q], f0[q]);
#pragma unroll
        for (int q = 0; q < 8; ++q) atomicAdd(&acc[b1 + q], f1[q]);
#pragma unroll
        for (int q = 0; q < 8; ++q) atomicAdd(&acc[b2 + q], f2[q]);
#pragma unroll
        for (int q = 0; q < 8; ++q) atomicAdd(&acc[b3 + q], f3[q]);
    }
    for (; i < end; i += 1024) {
        int p = bbuf[i];
        float4 r = *(const float4*)(hs + (size_t)(p & 0x3FFFF) * 8);
        float f[8];
        unpack8(r, f);
        int ba = (((unsigned)p) >> 18) * 9;
#pragma unroll
        for (int q = 0; q < 8; ++q) atomicAdd(&acc[ba + q], f[q]);
    }
    __syncthreads();
    // epilogue: one node per thread
    const int v = (b << BUCKSH) + t;
    if (v < n) {
        float4 rs = *(const float4*)(hs + (size_t)v * 8);
        float fs[8];
        unpack8(rs, fs);
        const float dv = dinv[v];
        float res[8];
#pragma unroll
        for (int q = 0; q < 8; ++q) {
            float val = dv * (acc[t * 9 + q] + fs[q]);
            if (L1) val = dv * fmaxf(val + bias[ch0 + q], 0.f);
            res[q] = val;
        }
        if (L1) {
            __half2 hr[4];
#pragma unroll
            for (int q = 0; q < 4; ++q)
                hr[q] = __floats2half2_rn(res[2 * q], res[2 * q + 1]);
            *(float4*)((__half*)o + (size_t)v * 8) = *(const float4*)hr;
        } else {
            float* op = (float*)o + (size_t)v * 8;
            *(float4*)op = make_float4(res[0], res[1], res[2], res[3]);
            *(float4*)(op + 4) = make_float4(res[4], res[5], res[6], res[7]);
        }
    }
}

// --- out = [preL|preH] @ W2 + b2 -----------------------------------------
__global__ void k_out(const float* __restrict__ preL,
                      const float* __restrict__ preH,
                      const float* __restrict__ W2,
                      const float* __restrict__ b2, float* __restrict__ out,
                      int n) {
    __shared__ float Ws[16 * 32];
    for (int i = threadIdx.x; i < 16 * 32; i += blockDim.x) Ws[i] = W2[i];
    __syncthreads();
    long long total = (long long)n * 32;
    long long i = (long long)blockIdx.x * blockDim.x + threadIdx.x;
    long long stride = (long long)gridDim.x * blockDim.x;
    for (; i < total; i += stride) {
        int v = (int)(i >> 5);
        int c = (int)(i & 31);
        const float* pl = preL + (size_t)v * 8;
        const float* ph = preH + (size_t)v * 8;
        float acc = b2[c];
#pragma unroll
        for (int j = 0; j < 8; ++j) acc += pl[j] * Ws[j * 32 + c];
#pragma unroll
        for (int j = 0; j < 8; ++j) acc += ph[j] * Ws[(8 + j) * 32 + c];
        out[i] = acc;
    }
}

static inline int blocks_for(long long total) {
    return (int)((total + TPB - 1) / TPB);
}

extern "C" void kernel_launch(void* const* d_in, const int* in_sizes, int n_in,
                              void* d_out, int out_size, void* d_ws,
                              size_t ws_size, hipStream_t stream) {
    const float* x = (const float*)d_in[0];
    const int* ei = (const int*)d_in[1];
    const float* W1 = (const float*)d_in[2];
    const float* b1 = (const float*)d_in[3];
    const float* W2 = (const float*)d_in[4];
    const float* b2 = (const float*)d_in[5];
    float* out = (float*)d_out;

    const int n = in_sizes[0] / 128;  // 200000 nodes
    const int E = in_sizes[1] / 2;    // 6400000 edges
    const int* src = ei;
    const int* dst = ei + E;
    const int nbuck = (n + BUCKN - 1) / BUCKN;  // 196 (<= 256 required)

    // workspace layout:
    //  dinv: n f32 | T: tables 25.6 MB {h1sL,h1sH,z1sL,z1sH (n*8 half each),
    //  preL,preH (n*8 f32 each)} | bbuf: E i32 (live through both layers) |
    //  hist/segsum/colsum/bstart
    char* ws = (char*)d_ws;
    float* dinv = (float*)ws;
    char* T = ws + (size_t)n * 4;
    __half* h1sL = (__half*)T;
    __half* h1sH = (__half*)(T + (size_t)n * 16);
    __half* z1sL = (__half*)(T + (size_t)n * 32);
    __half* z1sH = (__half*)(T + (size_t)n * 48);
    float* preL = (float*)(T + (size_t)n * 64);
    float* preH = (float*)(T + (size_t)n * 96);
    char* B = T + (size_t)n * 128;
    int* bbuf = (int*)B;
    int* hist = (int*)(B + (size_t)E * 4);

    size_t base_bytes = (size_t)n * 4 + (size_t)n * 128 + (size_t)E * 4;
    auto need = [&](int nbb) {
        return base_bytes +
               ((size_t)nbb + (size_t)nbb / SEGROWS + 2) * nbuck * 4 + 8192;
    };
    const int NBB =
        (ws_size >= need(2048)) ? 2048 : ((ws_size >= need(1024)) ? 1024 : 512);
    const int nseg = NBB / SEGROWS;
    const int chunk = (E + NBB - 1) / NBB;

    int* segsum = hist + (size_t)NBB * nbuck;
    int* colsum = segsum + (size_t)nseg * nbuck;
    int* bstart = colsum + nbuck;

    const int cb = (nbuck + 255) / 256;  // 1

    // --- bucket sort (no global atomics) ---
    k_hist<<<NBB, BINT, 0, stream>>>(dst, E, n, nbuck, chunk, hist);
    k_scanA1<<<dim3(cb, nseg), 256, 0, stream>>>(hist, nbuck, segsum);
    k_scanA2<<<cb, 256, 0, stream>>>(segsum, nbuck, nseg, colsum);
    k_scanB<<<1, 256, 0, stream>>>(colsum, nbuck, E, bstart);
    k_scanA3<<<dim3(cb, nseg), 256, 0, stream>>>(hist, nbuck, segsum);
    k_bin<<<NBB, BINT, 0, stream>>>(src, dst, E, n, nbuck, chunk, hist, bstart,
                                    bbuf);
    k_degb<<<nbuck, 1024, 0, stream>>>(bbuf, bstart, n, dinv);

    // --- layer 1 ---
    k_mm1<<<(n + MMN - 1) / MMN, 512, 0, stream>>>(x, W1, dinv, n, h1sL, h1sH);
    k_aggb<true><<<nbuck, 1024, 0, stream>>>(bbuf, bstart, dinv, h1sL, b1, 0,
                                             z1sL, n);
    k_aggb<true><<<nbuck, 1024, 0, stream>>>(bbuf, bstart, dinv, h1sH, b1, 8,
                                             z1sH, n);

    // --- layer 2 ---
    k_aggb<false><<<nbuck, 1024, 0, stream>>>(bbuf, bstart, dinv, z1sL, nullptr,
                                              0, preL, n);
    k_aggb<false><<<nbuck, 1024, 0, stream>>>(bbuf, bstart, dinv, z1sH, nullptr,
                                              8, preH, n);
    k_out<<<blocks_for((long long)n * 32), TPB, 0, stream>>>(preL, preH, W2, b2,
                                                             out, n);
}

// Round 16
// 463.755 us; speedup vs baseline: 3.2255x; 3.2255x over previous
//
#include <hip/hip_runtime.h>
#include <hip/hip_fp16.h>

// ---------------------------------------------------------------------------
// 2-layer GCN via device-built CSR + L2-resident scaled gather table.
// CSR build (two-level counting sort, no global atomics):
//   k_hist -> k_scanA1/A2 -> k_scanB -> k_scanA3 -> k_bin -> k_bucket
//   (bucket = 1024 dst nodes; k_bucket uses wave-shuffle scan).
// Layers (aggregate-first on layer 2; aggregation is linear):
//   h1s = dinv*(x@W1)                 fp16 table n x 16 (6.4 MB, rows 32 B)
//   z1s = dinv*relu(dinv*(agg+self)+b1)   fp16 table (k_gnode<L1>)
//   pre = dinv*(agg+self)             f32 n x 16     (k_gnode<L2>)
//   out = pre @ W2 + b2
// k_gnode: THREAD = NODE. Walks adj once; per edge 2 independent float4
// loads (the whole 32 B row), 16 f32 reg accumulators, 2-edge unroll.
// Replaces round-14's 4x k_gather4 (4 threads/node x 4B random hits on the
// same line = 4x L2 transactions + 4x adj re-reads) and round-15's LDS
// atomic k_aggb (343 us/pass: 8 dependent random-bank LDS atomics/edge).
// Region R (E*4 B) = bbuf during build, then {h1s, z1s, pre} exactly.
// ---------------------------------------------------------------------------

#define TPB 256
#define BINT 256
#define SEGROWS 64
#define BUCKSH 10                 // log2(nodes per bucket)
#define BUCKN (1 << BUCKSH)       // 1024 nodes per bucket
#define MMN 32                    // nodes per mm1 tile

__device__ __forceinline__ int clampi(int v, int n) {
    return v < 0 ? 0 : (v >= n ? n - 1 : v);
}

// --- per-block LDS histogram over contiguous edge range ------------------
__global__ __launch_bounds__(BINT) void k_hist(const int* __restrict__ dst,
                                               int E, int n, int nbuck,
                                               int chunk,
                                               int* __restrict__ hist) {
    __shared__ int lh[256];
    const int b = blockIdx.x;
    const int t = threadIdx.x;
    lh[t] = 0;
    __syncthreads();
    const int start = b * chunk;
    const int end = min(E, start + chunk);
    int i = start + t;
    for (; i + 3 * BINT < end; i += 4 * BINT) {
        int d0 = clampi(dst[i], n);
        int d1 = clampi(dst[i + BINT], n);
        int d2 = clampi(dst[i + 2 * BINT], n);
        int d3 = clampi(dst[i + 3 * BINT], n);
        atomicAdd(&lh[d0 >> BUCKSH], 1);
        atomicAdd(&lh[d1 >> BUCKSH], 1);
        atomicAdd(&lh[d2 >> BUCKSH], 1);
        atomicAdd(&lh[d3 >> BUCKSH], 1);
    }
    for (; i < end; i += BINT) atomicAdd(&lh[clampi(dst[i], n) >> BUCKSH], 1);
    __syncthreads();
    for (int k = t; k < nbuck; k += BINT) hist[b * nbuck + k] = lh[k];
}

// --- segmented column scan stage 1: per-segment column sums --------------
__global__ void k_scanA1(const int* __restrict__ hist, int nbuck,
                         int* __restrict__ segsum) {
    int k = blockIdx.x * blockDim.x + threadIdx.x;
    int seg = blockIdx.y;
    if (k >= nbuck) return;
    const int* row = hist + (size_t)seg * SEGROWS * nbuck + k;
    int sum = 0;
#pragma unroll
    for (int b = 0; b < SEGROWS; ++b) sum += row[(size_t)b * nbuck];
    segsum[seg * nbuck + k] = sum;
}

// --- stage 2: serial scan over segments (nseg <= 32) + colsum ------------
__global__ void k_scanA2(int* __restrict__ segsum, int nbuck, int nseg,
                         int* __restrict__ colsum) {
    int k = blockIdx.x * blockDim.x + threadIdx.x;
    if (k >= nbuck) return;
    int run = 0;
    for (int sg = 0; sg < nseg; ++sg) {
        int v = segsum[sg * nbuck + k];
        segsum[sg * nbuck + k] = run;
        run += v;
    }
    colsum[k] = run;
}

// --- exclusive scan of colsum -> bstart[0..nbuck] ------------------------
__global__ void k_scanB(const int* __restrict__ colsum, int nbuck, int E,
                        int* __restrict__ bstart) {
    __shared__ int s[256];
    const int t = threadIdx.x;
    int loc[4];
    int a = 0;
#pragma unroll
    for (int i = 0; i < 4; ++i) {
        int idx = 4 * t + i;
        loc[i] = (idx < nbuck) ? colsum[idx] : 0;
        a += loc[i];
    }
    s[t] = a;
    __syncthreads();
#pragma unroll
    for (int off = 1; off < 256; off <<= 1) {
        int v = (t >= off) ? s[t - off] : 0;
        __syncthreads();
        s[t] += v;
        __syncthreads();
    }
    int base = s[t] - a;
#pragma unroll
    for (int i = 0; i < 4; ++i) {
        int idx = 4 * t + i;
        if (idx < nbuck) bstart[idx] = base;
        base += loc[i];
    }
    if (t == 255) bstart[nbuck] = E;
}

// --- stage 3: rewrite hist rows to global exclusive prefix ---------------
__global__ void k_scanA3(int* __restrict__ hist, int nbuck,
                         const int* __restrict__ segsum) {
    int k = blockIdx.x * blockDim.x + threadIdx.x;
    int seg = blockIdx.y;
    if (k >= nbuck) return;
    int run = segsum[seg * nbuck + k];
    int* row = hist + (size_t)seg * SEGROWS * nbuck + k;
#pragma unroll
    for (int b = 0; b < SEGROWS; ++b) {
        int v = row[(size_t)b * nbuck];
        row[(size_t)b * nbuck] = run;
        run += v;
    }
}

// --- binning: LDS cursors, LDS atomics only; 4-way ILP -------------------
__global__ __launch_bounds__(BINT) void k_bin(const int* __restrict__ src,
                                              const int* __restrict__ dst,
                                              int E, int n, int nbuck,
                                              int chunk,
                                              const int* __restrict__ hist,
                                              const int* __restrict__ bstart,
                                              int* __restrict__ bbuf) {
    __shared__ int lcur[256];
    const int b = blockIdx.x;
    const int t = threadIdx.x;
    for (int k = t; k < nbuck; k += BINT)
        lcur[k] = bstart[k] + hist[b * nbuck + k];
    __syncthreads();
    const int start = b * chunk;
    const int end = min(E, start + chunk);
    int i = start + t;
    for (; i + 3 * BINT < end; i += 4 * BINT) {
        int s0 = clampi(src[i], n);
        int s1 = clampi(src[i + BINT], n);
        int s2 = clampi(src[i + 2 * BINT], n);
        int s3 = clampi(src[i + 3 * BINT], n);
        int d0 = clampi(dst[i], n);
        int d1 = clampi(dst[i + BINT], n);
        int d2 = clampi(dst[i + 2 * BINT], n);
        int d3 = clampi(dst[i + 3 * BINT], n);
        int p0 = atomicAdd(&lcur[d0 >> BUCKSH], 1);
        int p1 = atomicAdd(&lcur[d1 >> BUCKSH], 1);
        int p2 = atomicAdd(&lcur[d2 >> BUCKSH], 1);
        int p3 = atomicAdd(&lcur[d3 >> BUCKSH], 1);
        bbuf[p0] = ((d0 & (BUCKN - 1)) << 18) | s0;
        bbuf[p1] = ((d1 & (BUCKN - 1)) << 18) | s1;
        bbuf[p2] = ((d2 & (BUCKN - 1)) << 18) | s2;
        bbuf[p3] = ((d3 & (BUCKN - 1)) << 18) | s3;
    }
    for (; i < end; i += BINT) {
        int s0 = clampi(src[i], n);
        int d0 = clampi(dst[i], n);
        int p0 = atomicAdd(&lcur[d0 >> BUCKSH], 1);
        bbuf[p0] = ((d0 & (BUCKN - 1)) << 18) | s0;
    }
}

// --- per-bucket (1024 nodes, 1024 thr): hist -> wave-scan -> scatter -----
__global__ __launch_bounds__(1024) void k_bucket(const int* __restrict__ bbuf,
                                                 const int* __restrict__ bstart,
                                                 int n, int* __restrict__ rp,
                                                 float* __restrict__ dinv,
                                                 int* __restrict__ adj) {
    __shared__ int lcnt[1024];
    __shared__ int wsum[16];
    const int b = blockIdx.x;
    const int t = threadIdx.x;
    const int start = bstart[b];
    const int end = bstart[b + 1];

    lcnt[t] = 0;
    __syncthreads();
    {
        int i = start + t;
        for (; i + 3 * 1024 < end; i += 4 * 1024) {
            int p0 = bbuf[i], p1 = bbuf[i + 1024], p2 = bbuf[i + 2048],
                p3 = bbuf[i + 3072];
            atomicAdd(&lcnt[((unsigned)p0) >> 18], 1);
            atomicAdd(&lcnt[((unsigned)p1) >> 18], 1);
            atomicAdd(&lcnt[((unsigned)p2) >> 18], 1);
            atomicAdd(&lcnt[((unsigned)p3) >> 18], 1);
        }
        for (; i < end; i += 1024)
            atomicAdd(&lcnt[((unsigned)bbuf[i]) >> 18], 1);
    }
    __syncthreads();

    const int c = lcnt[t];
    int val = c;
#pragma unroll
    for (int off = 1; off < 64; off <<= 1) {
        int vv = __shfl_up(val, off, 64);
        if ((t & 63) >= off) val += vv;
    }
    if ((t & 63) == 63) wsum[t >> 6] = val;
    __syncthreads();
    if (t == 0) {
        int run = 0;
#pragma unroll
        for (int w = 0; w < 16; ++w) {
            int v = wsum[w];
            wsum[w] = run;
            run += v;
        }
    }
    __syncthreads();
    const int incl = val + wsum[t >> 6];
    const int v = (b << BUCKSH) + t;
    if (v < n) {
        rp[v] = start + incl;  // inclusive row end
        dinv[v] = rsqrtf((float)(c + 1));
    }
    lcnt[t] = start + incl - c;  // write cursor
    __syncthreads();

    {
        int i = start + t;
        for (; i + 3 * 1024 < end; i += 4 * 1024) {
            int p0 = bbuf[i], p1 = bbuf[i + 1024], p2 = bbuf[i + 2048],
                p3 = bbuf[i + 3072];
            int q0 = atomicAdd(&lcnt[((unsigned)p0) >> 18], 1);
            int q1 = atomicAdd(&lcnt[((unsigned)p1) >> 18], 1);
            int q2 = atomicAdd(&lcnt[((unsigned)p2) >> 18], 1);
            int q3 = atomicAdd(&lcnt[((unsigned)p3) >> 18], 1);
            adj[q0] = p0 & 0x3FFFF;
            adj[q1] = p1 & 0x3FFFF;
            adj[q2] = p2 & 0x3FFFF;
            adj[q3] = p3 & 0x3FFFF;
        }
        for (; i < end; i += 1024) {
            int p = bbuf[i];
            int q = atomicAdd(&lcnt[((unsigned)p) >> 18], 1);
            adj[q] = p & 0x3FFFF;
        }
    }
}

// --- h1s = dinv*(x@W1): LDS-staged tile (32 nodes), 512 thr, 16-ch table -
__global__ __launch_bounds__(512) void k_mm1(const float* __restrict__ x,
                                             const float* __restrict__ W,
                                             const float* __restrict__ dinv,
                                             int n, __half* __restrict__ hs) {
    __shared__ float Ws[128 * 16];
    __shared__ float xs[MMN * 132];
    const int t = threadIdx.x;
    for (int i = t; i < 128 * 16; i += 512) Ws[i] = W[i];
    const int node0 = blockIdx.x * MMN;
    {
        const float4* xg = (const float4*)(x + (size_t)node0 * 128);
#pragma unroll
        for (int it = 0; it < 2; ++it) {
            int idx = it * 512 + t;
            int row = idx >> 5;
            int c4 = idx & 31;
            if (node0 + row < n) {
                float4 v = xg[(size_t)row * 32 + c4];
                float* dp = &xs[row * 132 + c4 * 4];
                dp[0] = v.x;
                dp[1] = v.y;
                dp[2] = v.z;
                dp[3] = v.w;
            }
        }
    }
    __syncthreads();
    const int node = node0 + (t >> 4);
    const int c = t & 15;
    if (node < n) {
        const float4* xr4 = (const float4*)&xs[(t >> 4) * 132];
        float acc = 0.f;
#pragma unroll
        for (int q = 0; q < 32; ++q) {
            float4 xv = xr4[q];
            acc += xv.x * Ws[(4 * q + 0) * 16 + c] +
                   xv.y * Ws[(4 * q + 1) * 16 + c] +
                   xv.z * Ws[(4 * q + 2) * 16 + c] +
                   xv.w * Ws[(4 * q + 3) * 16 + c];
        }
        hs[(size_t)node * 16 + c] = __float2half(dinv[node] * acc);
    }
}

// --- helpers: unpack 8 halves (float4 raw) into 8 floats -----------------
__device__ __forceinline__ void unpack8(float4 r, float* f) {
    const __half2* hp = (const __half2*)&r;
#pragma unroll
    for (int q = 0; q < 4; ++q) {
        f[2 * q] = __low2float(hp[q]);
        f[2 * q + 1] = __high2float(hp[q]);
    }
}

// --- CSR gather, THREAD = NODE, 16 channels in registers -----------------
// per edge: 2 independent float4 loads (whole 32 B row); 2-edge unroll.
// L1: o = fp16 z1s (scaled by dinv after relu); else o = f32 pre.
template <bool L1>
__global__ void k_gnode(const int* __restrict__ rp, const int* __restrict__ adj,
                        const float* __restrict__ dinv,
                        const __half* __restrict__ hs,
                        const float* __restrict__ bias, void* __restrict__ o,
                        int n) {
    int v = blockIdx.x * blockDim.x + threadIdx.x;
    int stride = gridDim.x * blockDim.x;
    for (; v < n; v += stride) {
        const int start = (v == 0) ? 0 : rp[v - 1];
        const int end = rp[v];
        float acc[16];
#pragma unroll
        for (int q = 0; q < 16; ++q) acc[q] = 0.f;
        int k = start;
        for (; k + 1 < end; k += 2) {
            int s0 = adj[k], s1 = adj[k + 1];
            const float4* r0 = (const float4*)(hs + (size_t)s0 * 16);
            const float4* r1 = (const float4*)(hs + (size_t)s1 * 16);
            float4 a0 = r0[0], b0 = r0[1];
            float4 a1 = r1[0], b1 = r1[1];
            float f[16];
            unpack8(a0, f);
            unpack8(b0, f + 8);
#pragma unroll
            for (int q = 0; q < 16; ++q) acc[q] += f[q];
            unpack8(a1, f);
            unpack8(b1, f + 8);
#pragma unroll
            for (int q = 0; q < 16; ++q) acc[q] += f[q];
        }
        if (k < end) {
            int s0 = adj[k];
            const float4* r0 = (const float4*)(hs + (size_t)s0 * 16);
            float4 a0 = r0[0], b0 = r0[1];
            float f[16];
            unpack8(a0, f);
            unpack8(b0, f + 8);
#pragma unroll
            for (int q = 0; q < 16; ++q) acc[q] += f[q];
        }
        // self row + finalize
        const float4* rs = (const float4*)(hs + (size_t)v * 16);
        float fs[16];
        unpack8(rs[0], fs);
        unpack8(rs[1], fs + 8);
        const float dv = dinv[v];
        if (L1) {
            __half2 hr[8];
#pragma unroll
            for (int q = 0; q < 8; ++q) {
                float v0 = dv * fmaxf(dv * (acc[2 * q] + fs[2 * q]) +
                                          bias[2 * q], 0.f);
                float v1 = dv * fmaxf(dv * (acc[2 * q + 1] + fs[2 * q + 1]) +
                                          bias[2 * q + 1], 0.f);
                hr[q] = __floats2half2_rn(v0, v1);
            }
            float4* op = (float4*)((__half*)o + (size_t)v * 16);
            op[0] = *(const float4*)hr;
            op[1] = *(const float4*)(hr + 4);
        } else {
            float* op = (float*)o + (size_t)v * 16;
#pragma unroll
            for (int q = 0; q < 4; ++q) {
                *(float4*)(op + 4 * q) = make_float4(
                    dv * (acc[4 * q] + fs[4 * q]),
                    dv * (acc[4 * q + 1] + fs[4 * q + 1]),
                    dv * (acc[4 * q + 2] + fs[4 * q + 2]),
                    dv * (acc[4 * q + 3] + fs[4 * q + 3]));
            }
        }
    }
}

// --- out = pre @ W2 + b2   (pre: n x 16 f32) -----------------------------
__global__ void k_out(const float* __restrict__ pre,
                      const float* __restrict__ W2,
                      const float* __restrict__ b2, float* __restrict__ out,
                      int n) {
    __shared__ float Ws[16 * 32];
    for (int i = threadIdx.x; i < 16 * 32; i += blockDim.x) Ws[i] = W2[i];
    __syncthreads();
    long long total = (long long)n * 32;
    long long i = (long long)blockIdx.x * blockDim.x + threadIdx.x;
    long long stride = (long long)gridDim.x * blockDim.x;
    for (; i < total; i += stride) {
        int v = (int)(i >> 5);
        int c = (int)(i & 31);
        const float* pr = pre + (size_t)v * 16;
        float acc = b2[c];
#pragma unroll
        for (int j = 0; j < 16; ++j) acc += pr[j] * Ws[j * 32 + c];
        out[i] = acc;
    }
}

static inline int blocks_for(long long total) {
    return (int)((total + TPB - 1) / TPB);
}

extern "C" void kernel_launch(void* const* d_in, const int* in_sizes, int n_in,
                              void* d_out, int out_size, void* d_ws,
                              size_t ws_size, hipStream_t stream) {
    const float* x = (const float*)d_in[0];
    const int* ei = (const int*)d_in[1];
    const float* W1 = (const float*)d_in[2];
    const float* b1 = (const float*)d_in[3];
    const float* W2 = (const float*)d_in[4];
    const float* b2 = (const float*)d_in[5];
    float* out = (float*)d_out;

    const int n = in_sizes[0] / 128;  // 200000 nodes
    const int E = in_sizes[1] / 2;    // 6400000 edges
    const int* src = ei;
    const int* dst = ei + E;
    const int nbuck = (n + BUCKN - 1) / BUCKN;  // 196

    // workspace: dinv n f32 | rp n i32 | adj E i32 | R = E i32 (25.6 MB) |
    // hist/segsum/colsum/bstart.  R = bbuf during build, then
    // {h1s n*16 half (6.4) | z1s n*16 half (6.4) | pre n*16 f32 (12.8)}.
    char* ws = (char*)d_ws;
    float* dinv = (float*)ws;
    int* rp = (int*)(ws + (size_t)n * 4);
    int* adj = (int*)(ws + (size_t)n * 8);
    char* R = ws + (size_t)n * 8 + (size_t)E * 4;
    size_t base_bytes = (size_t)n * 8 + (size_t)E * 8;

    auto need = [&](int nbb) {
        return base_bytes +
               ((size_t)nbb + (size_t)nbb / SEGROWS + 2) * nbuck * 4 + 8192;
    };
    const int NBB =
        (ws_size >= need(2048)) ? 2048 : ((ws_size >= need(1024)) ? 1024 : 512);
    const int nseg = NBB / SEGROWS;
    const int chunk = (E + NBB - 1) / NBB;

    int* hist = (int*)(R + (size_t)E * 4);
    int* segsum = hist + (size_t)NBB * nbuck;
    int* colsum = segsum + (size_t)nseg * nbuck;
    int* bstart = colsum + nbuck;
    int* bbuf = (int*)R;

    __half* h1s = (__half*)R;
    __half* z1s = (__half*)(R + (size_t)n * 32);
    float* pre = (float*)(R + (size_t)n * 64);

    const int cb = (nbuck + 255) / 256;  // 1

    // --- CSR build (no global atomics) ---
    k_hist<<<NBB, BINT, 0, stream>>>(dst, E, n, nbuck, chunk, hist);
    k_scanA1<<<dim3(cb, nseg), 256, 0, stream>>>(hist, nbuck, segsum);
    k_scanA2<<<cb, 256, 0, stream>>>(segsum, nbuck, nseg, colsum);
    k_scanB<<<1, 256, 0, stream>>>(colsum, nbuck, E, bstart);
    k_scanA3<<<dim3(cb, nseg), 256, 0, stream>>>(hist, nbuck, segsum);
    k_bin<<<NBB, BINT, 0, stream>>>(src, dst, E, n, nbuck, chunk, hist, bstart,
                                    bbuf);
    k_bucket<<<nbuck, 1024, 0, stream>>>(bbuf, bstart, n, rp, dinv, adj);

    // --- layer 1 ---
    k_mm1<<<(n + MMN - 1) / MMN, 512, 0, stream>>>(x, W1, dinv, n, h1s);
    k_gnode<true><<<blocks_for(n), TPB, 0, stream>>>(rp, adj, dinv, h1s, b1,
                                                     z1s, n);
    // --- layer 2 ---
    k_gnode<false><<<blocks_for(n), TPB, 0, stream>>>(rp, adj, dinv, z1s,
                                                      nullptr, pre, n);
    k_out<<<blocks_for((long long)n * 32), TPB, 0, stream>>>(pre, W2, b2, out,
                                                             n);
}

// Round 17
// 355.164 us; speedup vs baseline: 4.2117x; 1.3057x over previous
//
#include <hip/hip_runtime.h>
#include <hip/hip_fp16.h>

// ---------------------------------------------------------------------------
// 2-layer GCN, CSR with rows sub-sorted by source-half (src<h | src>=h).
// Constraint discovered r16: random-gather hot set must be <= 4 MB (per-XCD
// L2). Instead of channel-splitting (r13/14: 4 passes x E line-touches),
// split by SOURCE: pass A walks A-edges only -> touches table rows [0,h)
// = 3.2 MB (L2-fit) with FULL 16-ch rows; pass B walks B-edges (rows [h,n)),
// accumulating onto pass-A partials. 2 passes x E/2 edges per layer = HALF
// the random line-touches of ch-split.
//   build: k_hist -> scans -> k_bin (unchanged, 1024-node buckets)
//          k_bucket2: within-bucket counting sort on key=(dlow<<1)|srchalf
//          -> adj + rp2[2v]=end-of-A, rp2[2v+1]=end-of-row + dinv
//   L1: k_mm1 (h1s = dinv*(x@W1), fp16 n x 16) ; gnA -> partial(f32) ;
//       gnB -> z1s = dinv*relu(dinv*(agg+self)+b1) (fp16)
//   L2: gnA(z1s) -> pre ; gnB -> pre = dinv*(agg+self) (f32, in place)
//   k_out: out = pre @ W2 + b2
// Thread = (node, row-half): lanes 2v,2v+1 load the 32 B row coalesced;
// 8 f32 accumulators each; 4-edge unroll. Region R = bbuf then {h1s,z1s,pre}.
// ---------------------------------------------------------------------------

#define TPB 256
#define BINT 256
#define SEGROWS 64
#define BUCKSH 10
#define BUCKN (1 << BUCKSH)
#define MMN 32

__device__ __forceinline__ int clampi(int v, int n) {
    return v < 0 ? 0 : (v >= n ? n - 1 : v);
}

// --- per-block LDS histogram over contiguous edge range ------------------
__global__ __launch_bounds__(BINT) void k_hist(const int* __restrict__ dst,
                                               int E, int n, int nbuck,
                                               int chunk,
                                               int* __restrict__ hist) {
    __shared__ int lh[256];
    const int b = blockIdx.x;
    const int t = threadIdx.x;
    lh[t] = 0;
    __syncthreads();
    const int start = b * chunk;
    const int end = min(E, start + chunk);
    int i = start + t;
    for (; i + 3 * BINT < end; i += 4 * BINT) {
        int d0 = clampi(dst[i], n);
        int d1 = clampi(dst[i + BINT], n);
        int d2 = clampi(dst[i + 2 * BINT], n);
        int d3 = clampi(dst[i + 3 * BINT], n);
        atomicAdd(&lh[d0 >> BUCKSH], 1);
        atomicAdd(&lh[d1 >> BUCKSH], 1);
        atomicAdd(&lh[d2 >> BUCKSH], 1);
        atomicAdd(&lh[d3 >> BUCKSH], 1);
    }
    for (; i < end; i += BINT) atomicAdd(&lh[clampi(dst[i], n) >> BUCKSH], 1);
    __syncthreads();
    for (int k = t; k < nbuck; k += BINT) hist[b * nbuck + k] = lh[k];
}

// --- segmented column scan stage 1 ---------------------------------------
__global__ void k_scanA1(const int* __restrict__ hist, int nbuck,
                         int* __restrict__ segsum) {
    int k = blockIdx.x * blockDim.x + threadIdx.x;
    int seg = blockIdx.y;
    if (k >= nbuck) return;
    const int* row = hist + (size_t)seg * SEGROWS * nbuck + k;
    int sum = 0;
#pragma unroll
    for (int b = 0; b < SEGROWS; ++b) sum += row[(size_t)b * nbuck];
    segsum[seg * nbuck + k] = sum;
}

// --- stage 2 --------------------------------------------------------------
__global__ void k_scanA2(int* __restrict__ segsum, int nbuck, int nseg,
                         int* __restrict__ colsum) {
    int k = blockIdx.x * blockDim.x + threadIdx.x;
    if (k >= nbuck) return;
    int run = 0;
    for (int sg = 0; sg < nseg; ++sg) {
        int v = segsum[sg * nbuck + k];
        segsum[sg * nbuck + k] = run;
        run += v;
    }
    colsum[k] = run;
}

// --- exclusive scan of colsum -> bstart ----------------------------------
__global__ void k_scanB(const int* __restrict__ colsum, int nbuck, int E,
                        int* __restrict__ bstart) {
    __shared__ int s[256];
    const int t = threadIdx.x;
    int loc[4];
    int a = 0;
#pragma unroll
    for (int i = 0; i < 4; ++i) {
        int idx = 4 * t + i;
        loc[i] = (idx < nbuck) ? colsum[idx] : 0;
        a += loc[i];
    }
    s[t] = a;
    __syncthreads();
#pragma unroll
    for (int off = 1; off < 256; off <<= 1) {
        int v = (t >= off) ? s[t - off] : 0;
        __syncthreads();
        s[t] += v;
        __syncthreads();
    }
    int base = s[t] - a;
#pragma unroll
    for (int i = 0; i < 4; ++i) {
        int idx = 4 * t + i;
        if (idx < nbuck) bstart[idx] = base;
        base += loc[i];
    }
    if (t == 255) bstart[nbuck] = E;
}

// --- stage 3 --------------------------------------------------------------
__global__ void k_scanA3(int* __restrict__ hist, int nbuck,
                         const int* __restrict__ segsum) {
    int k = blockIdx.x * blockDim.x + threadIdx.x;
    int seg = blockIdx.y;
    if (k >= nbuck) return;
    int run = segsum[seg * nbuck + k];
    int* row = hist + (size_t)seg * SEGROWS * nbuck + k;
#pragma unroll
    for (int b = 0; b < SEGROWS; ++b) {
        int v = row[(size_t)b * nbuck];
        row[(size_t)b * nbuck] = run;
        run += v;
    }
}

// --- binning: LDS cursors; 4-way ILP -------------------------------------
__global__ __launch_bounds__(BINT) void k_bin(const int* __restrict__ src,
                                              const int* __restrict__ dst,
                                              int E, int n, int nbuck,
                                              int chunk,
                                              const int* __restrict__ hist,
                                              const int* __restrict__ bstart,
                                              int* __restrict__ bbuf) {
    __shared__ int lcur[256];
    const int b = blockIdx.x;
    const int t = threadIdx.x;
    for (int k = t; k < nbuck; k += BINT)
        lcur[k] = bstart[k] + hist[b * nbuck + k];
    __syncthreads();
    const int start = b * chunk;
    const int end = min(E, start + chunk);
    int i = start + t;
    for (; i + 3 * BINT < end; i += 4 * BINT) {
        int s0 = clampi(src[i], n);
        int s1 = clampi(src[i + BINT], n);
        int s2 = clampi(src[i + 2 * BINT], n);
        int s3 = clampi(src[i + 3 * BINT], n);
        int d0 = clampi(dst[i], n);
        int d1 = clampi(dst[i + BINT], n);
        int d2 = clampi(dst[i + 2 * BINT], n);
        int d3 = clampi(dst[i + 3 * BINT], n);
        int p0 = atomicAdd(&lcur[d0 >> BUCKSH], 1);
        int p1 = atomicAdd(&lcur[d1 >> BUCKSH], 1);
        int p2 = atomicAdd(&lcur[d2 >> BUCKSH], 1);
        int p3 = atomicAdd(&lcur[d3 >> BUCKSH], 1);
        bbuf[p0] = ((d0 & (BUCKN - 1)) << 18) | s0;
        bbuf[p1] = ((d1 & (BUCKN - 1)) << 18) | s1;
        bbuf[p2] = ((d2 & (BUCKN - 1)) << 18) | s2;
        bbuf[p3] = ((d3 & (BUCKN - 1)) << 18) | s3;
    }
    for (; i < end; i += BINT) {
        int s0 = clampi(src[i], n);
        int d0 = clampi(dst[i], n);
        int p0 = atomicAdd(&lcur[d0 >> BUCKSH], 1);
        bbuf[p0] = ((d0 & (BUCKN - 1)) << 18) | s0;
    }
}

// --- per-bucket counting sort on key=(dlow<<1)|srchalf -> adj, rp2, dinv -
__global__ __launch_bounds__(1024) void k_bucket2(
    const int* __restrict__ bbuf, const int* __restrict__ bstart, int n, int h,
    int* __restrict__ rp2, float* __restrict__ dinv, int* __restrict__ adj) {
    __shared__ int lcnt[2048];
    __shared__ int wsum[16];
    const int b = blockIdx.x;
    const int t = threadIdx.x;
    const int start = bstart[b];
    const int end = bstart[b + 1];

    lcnt[t] = 0;
    lcnt[t + 1024] = 0;
    __syncthreads();
    {
        int i = start + t;
        for (; i + 3 * 1024 < end; i += 4 * 1024) {
            int p0 = bbuf[i], p1 = bbuf[i + 1024], p2 = bbuf[i + 2048],
                p3 = bbuf[i + 3072];
            int k0 = ((((unsigned)p0) >> 18) << 1) | ((p0 & 0x3FFFF) >= h);
            int k1 = ((((unsigned)p1) >> 18) << 1) | ((p1 & 0x3FFFF) >= h);
            int k2 = ((((unsigned)p2) >> 18) << 1) | ((p2 & 0x3FFFF) >= h);
            int k3 = ((((unsigned)p3) >> 18) << 1) | ((p3 & 0x3FFFF) >= h);
            atomicAdd(&lcnt[k0], 1);
            atomicAdd(&lcnt[k1], 1);
            atomicAdd(&lcnt[k2], 1);
            atomicAdd(&lcnt[k3], 1);
        }
        for (; i < end; i += 1024) {
            int p = bbuf[i];
            int k = ((((unsigned)p) >> 18) << 1) | ((p & 0x3FFFF) >= h);
            atomicAdd(&lcnt[k], 1);
        }
    }
    __syncthreads();

    const int c0 = lcnt[2 * t];
    const int c1 = lcnt[2 * t + 1];
    const int psum = c0 + c1;
    int val = psum;
#pragma unroll
    for (int off = 1; off < 64; off <<= 1) {
        int vv = __shfl_up(val, off, 64);
        if ((t & 63) >= off) val += vv;
    }
    if ((t & 63) == 63) wsum[t >> 6] = val;
    __syncthreads();
    if (t == 0) {
        int run = 0;
#pragma unroll
        for (int w = 0; w < 16; ++w) {
            int v = wsum[w];
            wsum[w] = run;
            run += v;
        }
    }
    __syncthreads();
    const int exclPair = val + wsum[t >> 6] - psum;  // excl prefix of key 2t
    const int v = (b << BUCKSH) + t;
    if (v < n) {
        rp2[2 * v] = start + exclPair + c0;             // end of A part
        rp2[2 * v + 1] = start + exclPair + c0 + c1;    // end of row
        dinv[v] = rsqrtf((float)(c0 + c1 + 1));
    }
    lcnt[2 * t] = start + exclPair;           // cursor key 2t
    lcnt[2 * t + 1] = start + exclPair + c0;  // cursor key 2t+1
    __syncthreads();

    {
        int i = start + t;
        for (; i + 3 * 1024 < end; i += 4 * 1024) {
            int p0 = bbuf[i], p1 = bbuf[i + 1024], p2 = bbuf[i + 2048],
                p3 = bbuf[i + 3072];
            int k0 = ((((unsigned)p0) >> 18) << 1) | ((p0 & 0x3FFFF) >= h);
            int k1 = ((((unsigned)p1) >> 18) << 1) | ((p1 & 0x3FFFF) >= h);
            int k2 = ((((unsigned)p2) >> 18) << 1) | ((p2 & 0x3FFFF) >= h);
            int k3 = ((((unsigned)p3) >> 18) << 1) | ((p3 & 0x3FFFF) >= h);
            int q0 = atomicAdd(&lcnt[k0], 1);
            int q1 = atomicAdd(&lcnt[k1], 1);
            int q2 = atomicAdd(&lcnt[k2], 1);
            int q3 = atomicAdd(&lcnt[k3], 1);
            adj[q0] = p0 & 0x3FFFF;
            adj[q1] = p1 & 0x3FFFF;
            adj[q2] = p2 & 0x3FFFF;
            adj[q3] = p3 & 0x3FFFF;
        }
        for (; i < end; i += 1024) {
            int p = bbuf[i];
            int k = ((((unsigned)p) >> 18) << 1) | ((p & 0x3FFFF) >= h);
            int q = atomicAdd(&lcnt[k], 1);
            adj[q] = p & 0x3FFFF;
        }
    }
}

// --- h1s = dinv*(x@W1): LDS-staged tile, 16-ch fp16 table ----------------
__global__ __launch_bounds__(512) void k_mm1(const float* __restrict__ x,
                                             const float* __restrict__ W,
                                             const float* __restrict__ dinv,
                                             int n, __half* __restrict__ hs) {
    __shared__ float Ws[128 * 16];
    __shared__ float xs[MMN * 132];
    const int t = threadIdx.x;
    for (int i = t; i < 128 * 16; i += 512) Ws[i] = W[i];
    const int node0 = blockIdx.x * MMN;
    {
        const float4* xg = (const float4*)(x + (size_t)node0 * 128);
#pragma unroll
        for (int it = 0; it < 2; ++it) {
            int idx = it * 512 + t;
            int row = idx >> 5;
            int c4 = idx & 31;
            if (node0 + row < n) {
                float4 v = xg[(size_t)row * 32 + c4];
                float* dp = &xs[row * 132 + c4 * 4];
                dp[0] = v.x;
                dp[1] = v.y;
                dp[2] = v.z;
                dp[3] = v.w;
            }
        }
    }
    __syncthreads();
    const int node = node0 + (t >> 4);
    const int c = t & 15;
    if (node < n) {
        const float4* xr4 = (const float4*)&xs[(t >> 4) * 132];
        float acc = 0.f;
#pragma unroll
        for (int q = 0; q < 32; ++q) {
            float4 xv = xr4[q];
            acc += xv.x * Ws[(4 * q + 0) * 16 + c] +
                   xv.y * Ws[(4 * q + 1) * 16 + c] +
                   xv.z * Ws[(4 * q + 2) * 16 + c] +
                   xv.w * Ws[(4 * q + 3) * 16 + c];
        }
        hs[(size_t)node * 16 + c] = __float2half(dinv[node] * acc);
    }
}

__device__ __forceinline__ void unpack8(float4 r, float* f) {
    const __half2* hp = (const __half2*)&r;
#pragma unroll
    for (int q = 0; q < 4; ++q) {
        f[2 * q] = __low2float(hp[q]);
        f[2 * q + 1] = __high2float(hp[q]);
    }
}

// --- src-split gather. thread = (node, row-half). 8 f32 accumulators. ----
// PASSA (PASSB=false): acc=0, walk [rowstart, rp2[2v]) -> store f32 partial.
// PASSB: acc=partial, walk [rp2[2v], rp2[2v+1]), add self, finalize:
//   L1: z1s = dinv*relu(dinv*(...)+bias) fp16 ; else pre = dinv*(...) f32.
template <bool L1, bool PASSB>
__global__ void k_gn(const int* __restrict__ rp2,
                     const int* __restrict__ bstart,
                     const int* __restrict__ adj,
                     const float* __restrict__ dinv,
                     const __half* __restrict__ hs,
                     const float* __restrict__ bias,
                     float* __restrict__ partial, void* __restrict__ o,
                     int n) {
    long long total = 2LL * n;
    long long i = (long long)blockIdx.x * blockDim.x + threadIdx.x;
    long long stride = (long long)gridDim.x * blockDim.x;
    for (; i < total; i += stride) {
        const int v = (int)(i >> 1);
        const int hf = (int)(i & 1);
        const int rowstart =
            ((v & (BUCKN - 1)) == 0) ? bstart[v >> BUCKSH] : rp2[2 * v - 1];
        const int s = PASSB ? rp2[2 * v] : rowstart;
        const int e = PASSB ? rp2[2 * v + 1] : rp2[2 * v];
        float acc[8];
        if (PASSB) {
            const float4* pp =
                (const float4*)(partial + (size_t)v * 16 + hf * 8);
            float4 a = pp[0], b = pp[1];
            acc[0] = a.x; acc[1] = a.y; acc[2] = a.z; acc[3] = a.w;
            acc[4] = b.x; acc[5] = b.y; acc[6] = b.z; acc[7] = b.w;
        } else {
#pragma unroll
            for (int q = 0; q < 8; ++q) acc[q] = 0.f;
        }
        int k = s;
        for (; k + 3 < e; k += 4) {
            int s0 = adj[k], s1 = adj[k + 1], s2 = adj[k + 2], s3 = adj[k + 3];
            float4 r0 = *(const float4*)(hs + (size_t)s0 * 16 + hf * 8);
            float4 r1 = *(const float4*)(hs + (size_t)s1 * 16 + hf * 8);
            float4 r2 = *(const float4*)(hs + (size_t)s2 * 16 + hf * 8);
            float4 r3 = *(const float4*)(hs + (size_t)s3 * 16 + hf * 8);
            float f0[8], f1[8], f2[8], f3[8];
            unpack8(r0, f0);
            unpack8(r1, f1);
            unpack8(r2, f2);
            unpack8(r3, f3);
#pragma unroll
            for (int q = 0; q < 8; ++q)
                acc[q] += (f0[q] + f1[q]) + (f2[q] + f3[q]);
        }
        for (; k < e; ++k) {
            float4 r = *(const float4*)(hs + (size_t)adj[k] * 16 + hf * 8);
            float f[8];
            unpack8(r, f);
#pragma unroll
            for (int q = 0; q < 8; ++q) acc[q] += f[q];
        }
        if (!PASSB) {
            float* pp = partial + (size_t)v * 16 + hf * 8;
            *(float4*)pp = make_float4(acc[0], acc[1], acc[2], acc[3]);
            *(float4*)(pp + 4) = make_float4(acc[4], acc[5], acc[6], acc[7]);
        } else {
            float4 rs = *(const float4*)(hs + (size_t)v * 16 + hf * 8);
            float fs[8];
            unpack8(rs, fs);
            const float dv = dinv[v];
            if (L1) {
                __half2 hr[4];
#pragma unroll
                for (int q = 0; q < 4; ++q) {
                    float v0 = dv * fmaxf(dv * (acc[2 * q] + fs[2 * q]) +
                                              bias[hf * 8 + 2 * q],
                                          0.f);
                    float v1 = dv * fmaxf(dv * (acc[2 * q + 1] + fs[2 * q + 1]) +
                                              bias[hf * 8 + 2 * q + 1],
                                          0.f);
                    hr[q] = __floats2half2_rn(v0, v1);
                }
                *(float4*)((__half*)o + (size_t)v * 16 + hf * 8) =
                    *(const float4*)hr;
            } else {
                float* op = (float*)o + (size_t)v * 16 + hf * 8;
                *(float4*)op =
                    make_float4(dv * (acc[0] + fs[0]), dv * (acc[1] + fs[1]),
                                dv * (acc[2] + fs[2]), dv * (acc[3] + fs[3]));
                *(float4*)(op + 4) =
                    make_float4(dv * (acc[4] + fs[4]), dv * (acc[5] + fs[5]),
                                dv * (acc[6] + fs[6]), dv * (acc[7] + fs[7]));
            }
        }
    }
}

// --- out = pre @ W2 + b2 --------------------------------------------------
__global__ void k_out(const float* __restrict__ pre,
                      const float* __restrict__ W2,
                      const float* __restrict__ b2, float* __restrict__ out,
                      int n) {
    __shared__ float Ws[16 * 32];
    for (int i = threadIdx.x; i < 16 * 32; i += blockDim.x) Ws[i] = W2[i];
    __syncthreads();
    long long total = (long long)n * 32;
    long long i = (long long)blockIdx.x * blockDim.x + threadIdx.x;
    long long stride = (long long)gridDim.x * blockDim.x;
    for (; i < total; i += stride) {
        int v = (int)(i >> 5);
        int c = (int)(i & 31);
        const float* pr = pre + (size_t)v * 16;
        float acc = b2[c];
#pragma unroll
        for (int j = 0; j < 16; ++j) acc += pr[j] * Ws[j * 32 + c];
        out[i] = acc;
    }
}

static inline int blocks_for(long long total) {
    return (int)((total + TPB - 1) / TPB);
}

extern "C" void kernel_launch(void* const* d_in, const int* in_sizes, int n_in,
                              void* d_out, int out_size, void* d_ws,
                              size_t ws_size, hipStream_t stream) {
    const float* x = (const float*)d_in[0];
    const int* ei = (const int*)d_in[1];
    const float* W1 = (const float*)d_in[2];
    const float* b1 = (const float*)d_in[3];
    const float* W2 = (const float*)d_in[4];
    const float* b2 = (const float*)d_in[5];
    float* out = (float*)d_out;

    const int n = in_sizes[0] / 128;  // 200000 nodes
    const int E = in_sizes[1] / 2;    // 6400000 edges
    const int* src = ei;
    const int* dst = ei + E;
    const int nbuck = (n + BUCKN - 1) / BUCKN;  // 196
    const int h = (n + 1) / 2;                  // src-half boundary

    // workspace: dinv n | rp2 2n | adj E | R = E i32 | hist...
    // R = bbuf during build, then {h1s 32n B | z1s 32n B | pre 64n B} = 128n.
    char* ws = (char*)d_ws;
    float* dinv = (float*)ws;
    int* rp2 = (int*)(ws + (size_t)n * 4);
    int* adj = (int*)(ws + (size_t)n * 12);
    char* R = ws + (size_t)n * 12 + (size_t)E * 4;
    size_t base_bytes = (size_t)n * 12 + (size_t)E * 8;

    auto need = [&](int nbb) {
        return base_bytes +
               ((size_t)nbb + (size_t)nbb / SEGROWS + 2) * nbuck * 4 + 8192;
    };
    const int NBB =
        (ws_size >= need(2048)) ? 2048 : ((ws_size >= need(1024)) ? 1024 : 512);
    const int nseg = NBB / SEGROWS;
    const int chunk = (E + NBB - 1) / NBB;

    int* hist = (int*)(R + (size_t)E * 4);
    int* segsum = hist + (size_t)NBB * nbuck;
    int* colsum = segsum + (size_t)nseg * nbuck;
    int* bstart = colsum + nbuck;
    int* bbuf = (int*)R;

    __half* h1s = (__half*)R;
    __half* z1s = (__half*)(R + (size_t)n * 32);
    float* pre = (float*)(R + (size_t)n * 64);

    const int cb = (nbuck + 255) / 256;  // 1

    // --- build ---
    k_hist<<<NBB, BINT, 0, stream>>>(dst, E, n, nbuck, chunk, hist);
    k_scanA1<<<dim3(cb, nseg), 256, 0, stream>>>(hist, nbuck, segsum);
    k_scanA2<<<cb, 256, 0, stream>>>(segsum, nbuck, nseg, colsum);
    k_scanB<<<1, 256, 0, stream>>>(colsum, nbuck, E, bstart);
    k_scanA3<<<dim3(cb, nseg), 256, 0, stream>>>(hist, nbuck, segsum);
    k_bin<<<NBB, BINT, 0, stream>>>(src, dst, E, n, nbuck, chunk, hist, bstart,
                                    bbuf);
    k_bucket2<<<nbuck, 1024, 0, stream>>>(bbuf, bstart, n, h, rp2, dinv, adj);

    // --- layer 1 ---
    k_mm1<<<(n + MMN - 1) / MMN, 512, 0, stream>>>(x, W1, dinv, n, h1s);
    k_gn<true, false><<<blocks_for(2LL * n), TPB, 0, stream>>>(
        rp2, bstart, adj, dinv, h1s, b1, pre, nullptr, n);
    k_gn<true, true><<<blocks_for(2LL * n), TPB, 0, stream>>>(
        rp2, bstart, adj, dinv, h1s, b1, pre, z1s, n);

    // --- layer 2 ---
    k_gn<false, false><<<blocks_for(2LL * n), TPB, 0, stream>>>(
        rp2, bstart, adj, dinv, z1s, nullptr, pre, nullptr, n);
    k_gn<false, true><<<blocks_for(2LL * n), TPB, 0, stream>>>(
        rp2, bstart, adj, dinv, z1s, nullptr, pre, pre, n);

    k_out<<<blocks_for((long long)n * 32), TPB, 0, stream>>>(pre, W2, b2, out,
                                                             n);
}